// Round 6
// baseline (160.093 us; speedup 1.0000x reference)
//
#include <hip/hip_runtime.h>

#define HIDDEN 1024
#define NTOK (8 * 2048)   // B*S = 16384 tokens
#define BM 256
#define BN 128
#define BK 32
#define NT (HIDDEN / BK)  // 32 K-tiles

typedef __attribute__((ext_vector_type(4))) float f32x4;
typedef __attribute__((ext_vector_type(8))) short bf16x8;
typedef __attribute__((ext_vector_type(4))) unsigned short u16x4;
typedef __attribute__((ext_vector_type(8))) unsigned short u16x8;

typedef __attribute__((address_space(3))) unsigned int lds_u32;
typedef __attribute__((address_space(1))) unsigned int glb_u32;

__device__ inline unsigned short f2b(float f) {
    unsigned int u = __float_as_uint(f);
    u += 0x7fffu + ((u >> 16) & 1u);   // round-to-nearest-even
    return (unsigned short)(u >> 16);
}
__device__ inline float b2f(unsigned short u) {
    return __uint_as_float(((unsigned int)u) << 16);
}

// ---------------- fp32 -> bf16 convert, all 4 arrays in one launch ----------
__global__ __launch_bounds__(256) void cvt_all(
    const float4* __restrict__ x1, const float4* __restrict__ wq,
    const float4* __restrict__ wk, const float4* __restrict__ wv,
    u16x4* __restrict__ dst) {
    const int NX = NTOK * HIDDEN / 4;
    const int NW = HIDDEN * HIDDEN / 4;
    const int total = NX + 3 * NW;
    const int stride = gridDim.x * blockDim.x;
    for (int i = blockIdx.x * blockDim.x + threadIdx.x; i < total; i += stride) {
        const float4* s; int o;
        if (i < NX)               { s = x1; o = i; }
        else if (i < NX + NW)     { s = wq; o = i - NX; }
        else if (i < NX + 2 * NW) { s = wk; o = i - NX - NW; }
        else                      { s = wv; o = i - NX - 2 * NW; }
        float4 x = s[o];
        u16x4 r;
        r[0] = f2b(x.x); r[1] = f2b(x.y); r[2] = f2b(x.z); r[3] = f2b(x.w);
        dst[i] = r;
    }
}

// ---------------- fused QKV GEMM: 256x128 tile, prefetch-2 pipeline ---------
// C = X (16384x1024) * W^T + bias ; 64 m-tiles x 24 n-tiles = 1536 blocks.
// 4 waves (2M x 2N) of 128x64. TRIPLE-buffered LDS (3x24KB=72KB, 2 blocks/CU);
// iter j stages tile j+2, computes tile j, ends with counted
// s_waitcnt vmcnt(6) + raw s_barrier -> staging loads stay in flight across
// the barrier (never drain to 0 in steady state); each tile has >1 full
// iteration of slack to cover the L2/HBM round trip.
// Swizzle: 16B slot ^= (row>>1)&3  -> frag reads spread evenly over banks.
__global__ __launch_bounds__(256, 2) void qkv_gemm(
    const unsigned short* __restrict__ Xb,
    const unsigned short* __restrict__ Wb,
    const float* __restrict__ bqp, const float* __restrict__ bkp,
    const float* __restrict__ bvp,
    unsigned short* __restrict__ QKV) {
    // per buffer: A 256x32 (16 KB) @ [0..8191], B 128x32 (8 KB) @ [8192..12287]
    __shared__ __align__(16) unsigned short sb[3][12288];

    const int tid = threadIdx.x;
    const int lane = tid & 63, wave = tid >> 6;
    const int wm = wave >> 1, wn = wave & 1;      // 2x2 wave grid, 128x64 each

    // 2D super-tile XCD map: 64 super-tiles of (4 mt x 6 nt) = 24 blocks.
    const int bid = blockIdx.x;
    const int xcd = bid & 7;
    const int i6 = bid >> 3;            // 0..191
    const int st = i6 / 24;             // 0..7
    const int w = i6 % 24;              // 0..23
    const int g = xcd * 8 + st;         // global super-tile 0..63
    const int mt = (g >> 2) * 4 + w / 6;    // 0..63
    const int nt = (g & 3) * 6 + w % 6;     // 0..23
    const int mat = nt >> 3;                // 0=q 1=k 2=v
    const int col0 = (nt & 7) * BN;
    const int row0 = mt * BM;

    const unsigned short* Ag = Xb + (size_t)row0 * HIDDEN;
    const unsigned short* Bg = Wb + (size_t)mat * (HIDDEN * HIDDEN)
                                  + (size_t)col0 * HIDDEN;
    const float* bias = (mat == 0) ? bqp : ((mat == 1) ? bkp : bvp);
    unsigned short* Out = QKV + (size_t)mat * ((size_t)NTOK * HIDDEN);

    // staging: 1536 16B-chunks (A:1024, B:512), 6 per thread (256 thr).
    // source col pre-swizzled: slot ^ ((row>>1)&3); LDS dest linear.
    const unsigned short* srcb[6];
    int dstoff[6];
#pragma unroll
    for (int c = 0; c < 6; ++c) {
        const int gidx = c * 256 + tid;
        const int slot = gidx & 3;
        if (gidx < 1024) {
            const int r = gidx >> 2;
            srcb[c] = Ag + (size_t)r * HIDDEN + (slot ^ ((r >> 1) & 3)) * 8;
        } else {
            const int r = (gidx - 1024) >> 2;
            srcb[c] = Bg + (size_t)r * HIDDEN + (slot ^ ((r >> 1) & 3)) * 8;
        }
        dstoff[c] = gidx * 8;
    }

    // frag read bases (halfword offsets), swizzled k-slot
    const int fr = lane & 15;
    const int kq = lane >> 4;            // 16B slot within 32-elem row
    const int sx = (fr >> 1) & 3;
    const int aoff = (wm * 128 + fr) * BK + ((kq ^ sx) * 8);
    const int boff = 8192 + (wn * 64 + fr) * BK + ((kq ^ sx) * 8);

    // prologue: stage tiles 0 and 1
#pragma unroll
    for (int c = 0; c < 6; ++c)
        __builtin_amdgcn_global_load_lds((const glb_u32*)(srcb[c]),
                                         (lds_u32*)(&sb[0][0] + dstoff[c]), 16, 0, 0);
#pragma unroll
    for (int c = 0; c < 6; ++c)
        __builtin_amdgcn_global_load_lds((const glb_u32*)(srcb[c] + BK),
                                         (lds_u32*)(&sb[1][0] + dstoff[c]), 16, 0, 0);
    asm volatile("s_waitcnt vmcnt(6)" ::: "memory");   // tile 0 landed
    __builtin_amdgcn_s_barrier();

    f32x4 acc[8][4] = {};

    int rb = 0;    // buffer holding tile j
    int pb = 2;    // buffer receiving tile j+2
    for (int j = 0; j < NT; ++j) {
        // stage tile j+2 (stays in flight across this iteration's barrier)
        if (j + 2 < NT) {
            unsigned short* dbuf = &sb[pb][0];
#pragma unroll
            for (int c = 0; c < 6; ++c)
                __builtin_amdgcn_global_load_lds(
                    (const glb_u32*)(srcb[c] + (j + 2) * BK),
                    (lds_u32*)(dbuf + dstoff[c]), 16, 0, 0);
        }
        // compute tile j: 4 B-frags held, 8 A-frags streamed
        const unsigned short* buf = &sb[rb][0];
        bf16x8 bfr[4];
#pragma unroll
        for (int n = 0; n < 4; ++n)
            bfr[n] = *(const bf16x8*)(buf + boff + n * (16 * BK));
#pragma unroll
        for (int m = 0; m < 8; ++m) {
            const bf16x8 afr = *(const bf16x8*)(buf + aoff + m * (16 * BK));
#pragma unroll
            for (int n = 0; n < 4; ++n)
                acc[m][n] = __builtin_amdgcn_mfma_f32_16x16x32_bf16(
                    afr, bfr[n], acc[m][n], 0, 0, 0);
        }
        // counted wait: tile j+1's 6 loads done; tile j+2's 6 stay in flight.
        if (j + 2 < NT) {
            asm volatile("s_waitcnt vmcnt(6) lgkmcnt(0)" ::: "memory");
            __builtin_amdgcn_s_barrier();
        } else if (j + 1 < NT) {
            asm volatile("s_waitcnt vmcnt(0) lgkmcnt(0)" ::: "memory");
            __builtin_amdgcn_s_barrier();
        }
        rb = (rb == 2) ? 0 : rb + 1;
        pb = (pb == 2) ? 0 : pb + 1;
    }

    // epilogue: bias add, bf16 store. C/D map: col=lane&15, row=(lane>>4)*4+jj
    const int fq = lane >> 4;
    float bvv[4];
#pragma unroll
    for (int n = 0; n < 4; ++n) bvv[n] = bias[col0 + wn * 64 + n * 16 + fr];
#pragma unroll
    for (int m = 0; m < 8; ++m) {
#pragma unroll
        for (int n = 0; n < 4; ++n) {
            const int colg = col0 + wn * 64 + n * 16 + fr;
#pragma unroll
            for (int jj = 0; jj < 4; ++jj) {
                const int rowg = row0 + wm * 128 + m * 16 + fq * 4 + jj;
                Out[(size_t)rowg * HIDDEN + colg] = f2b(acc[m][n][jj] + bvv[n]);
            }
        }
    }
}

// ---------------- per-token attention over the HEAD dim ----------------------
// one wave per token; lane = h*8+g computes score[h][g]; softmax over g.
__global__ __launch_bounds__(256) void attn_k(const unsigned short* __restrict__ QKV,
                                              float* __restrict__ out) {
    __shared__ unsigned short sQ[4][HIDDEN];
    __shared__ unsigned short sK[4][HIDDEN];
    __shared__ unsigned short sV[4][HIDDEN];
    __shared__ float sA[4][64];

    const int t = threadIdx.x, lane = t & 63, wave = t >> 6;
    const int token = blockIdx.x * 4 + wave;
    const size_t base = (size_t)token * HIDDEN;
    const unsigned short* q = QKV + base;
    const unsigned short* k = QKV + (size_t)NTOK * HIDDEN + base;
    const unsigned short* v = QKV + 2 * (size_t)NTOK * HIDDEN + base;

#pragma unroll
    for (int i = 0; i < 2; ++i) {
        const int off = (i * 64 + lane) * 8;
        *(u16x8*)&sQ[wave][off] = *(const u16x8*)&q[off];
        *(u16x8*)&sK[wave][off] = *(const u16x8*)&k[off];
        *(u16x8*)&sV[wave][off] = *(const u16x8*)&v[off];
    }
    __syncthreads();

    const int h = lane >> 3, g = lane & 7;
    float sc = 0.f;
    const unsigned short* Qr = &sQ[wave][h * 128];
    const unsigned short* Kr = &sK[wave][g * 128];
#pragma unroll
    for (int d = 0; d < 128; d += 8) {
        u16x8 qv = *(const u16x8*)&Qr[d];
        u16x8 kv = *(const u16x8*)&Kr[d];
#pragma unroll
        for (int j = 0; j < 8; ++j) sc += b2f(qv[j]) * b2f(kv[j]);
    }
    sc *= -0.08838834764831845f;   // NEGATED scale, faithful to source quirk

    float mx = sc;
#pragma unroll
    for (int o = 1; o < 8; o <<= 1) mx = fmaxf(mx, __shfl_xor(mx, o, 64));
    const float e = __expf(sc - mx);
    float sm = e;
#pragma unroll
    for (int o = 1; o < 8; o <<= 1) sm += __shfl_xor(sm, o, 64);
    sA[wave][lane] = e / sm;
    __syncthreads();

    const int c = lane & 7;        // 16-wide d-chunk within head
    float ov[16];
#pragma unroll
    for (int j = 0; j < 16; ++j) ov[j] = 0.f;
    const float* Ar = &sA[wave][h * 8];
#pragma unroll
    for (int gg = 0; gg < 8; ++gg) {
        const float a = Ar[gg];
        const unsigned short* Vr = &sV[wave][gg * 128 + c * 16];
#pragma unroll
        for (int j = 0; j < 16; ++j) ov[j] += a * b2f(Vr[j]);
    }
    float* op = out + base + lane * 16;   // lane*16 == h*128 + c*16
#pragma unroll
    for (int j = 0; j < 16; j += 4) {
        float4 r = make_float4(ov[j], ov[j + 1], ov[j + 2], ov[j + 3]);
        *(float4*)&op[j] = r;
    }
}

extern "C" void kernel_launch(void* const* d_in, const int* in_sizes, int n_in,
                              void* d_out, int out_size, void* d_ws, size_t ws_size,
                              hipStream_t stream) {
    const float* x1 = (const float*)d_in[0];
    const float* Wq = (const float*)d_in[1];
    const float* bq = (const float*)d_in[2];
    const float* Wk = (const float*)d_in[3];
    const float* bk = (const float*)d_in[4];
    const float* Wv = (const float*)d_in[5];
    const float* bv = (const float*)d_in[6];
    float* out = (float*)d_out;

    // workspace layout (bf16 as ushort): Xb | Wb(q,k,v) | QKV  -> 140.5 MB
    unsigned short* Xb  = (unsigned short*)d_ws;
    unsigned short* Wb  = Xb + (size_t)NTOK * HIDDEN;
    unsigned short* QKV = Wb + 3 * (size_t)HIDDEN * HIDDEN;

    cvt_all<<<2048, 256, 0, stream>>>((const float4*)x1, (const float4*)Wq,
                                      (const float4*)Wk, (const float4*)Wv,
                                      (u16x4*)Xb);

    qkv_gemm<<<dim3(1536), 256, 0, stream>>>(Xb, Wb, bq, bk, bv, QKV);

    attn_k<<<NTOK / 4, 256, 0, stream>>>(QKV, out);
}